// Round 4
// baseline (120.723 us; speedup 1.0000x reference)
//
#include <hip/hip_runtime.h>
#include <hip/hip_bf16.h>

// Problem constants (setup_inputs): B=2, N=16384, M=1024, IN=OUT=256
#define NPTS    32768
#define K_DIM   256
#define O_DIM   256
#define M_ATOMS 1024

typedef __attribute__((ext_vector_type(8))) short short8;
typedef __attribute__((ext_vector_type(4))) float f32x4;

__device__ __forceinline__ unsigned short bf16_rn(float f) {
  unsigned u = __float_as_uint(f);
  unsigned r = u + 0x7FFFu + ((u >> 16) & 1u);
  return (unsigned short)(r >> 16);
}

__device__ __forceinline__ void cvt8(const f32x4 f0, const f32x4 f1,
                                     short8* h, short8* l) {
#pragma unroll
  for (int j = 0; j < 4; ++j) {
    unsigned short h0 = bf16_rn(f0[j]);
    (*h)[j] = (short)h0;
    (*l)[j] = (short)bf16_rn(f0[j] - __uint_as_float((unsigned)h0 << 16));
    unsigned short h1 = bf16_rn(f1[j]);
    (*h)[j + 4] = (short)h1;
    (*l)[j + 4] = (short)bf16_rn(f1[j] - __uint_as_float((unsigned)h1 << 16));
  }
}

// async global->LDS, 16B per lane; LDS dest = wave-uniform base + lane*16
__device__ __forceinline__ void async16(void* l, const void* g) {
  __builtin_amdgcn_global_load_lds(
      (const __attribute__((address_space(1))) void*)g,
      (__attribute__((address_space(3))) void*)l, 16, 0, 0);
}

// Kernel 0: W -> bf16 hi/lo in MFMA-fragment-major layout [kc8][ct16][lane64][8].
// col = ct*16 + (lane&15), k = kc*32 + (lane>>4)*8 + e  (layout verified R1-R3).
__global__ __launch_bounds__(256) void wprep_kernel(const float* __restrict__ W,
                                                    unsigned short* __restrict__ whF,
                                                    unsigned short* __restrict__ wlF) {
  int t = blockIdx.x * 256 + threadIdx.x;   // 0..8191
  int lane = t & 63;
  int ct = (t >> 6) & 15;
  int kc = t >> 10;
  int col = ct * 16 + (lane & 15);
  int k0 = kc * 32 + (lane >> 4) * 8;
  const float* src = W + (size_t)col * K_DIM + k0;
  f32x4 f0 = *(const f32x4*)(src);
  f32x4 f1 = *(const f32x4*)(src + 4);
  short8 h, l;
  cvt8(f0, f1, &h, &l);
  *(short8*)(whF + (size_t)t * 8) = h;
  *(short8*)(wlF + (size_t)t * 8) = l;
}

// Fused GEMM + omega + sin. 512 blocks x 256 threads.
// Wave = 32 points (2 row-tiles) x 128 cols (col-half): each bh/bl LDS read
// feeds 6 MFMA. B staged in 32KB chunks (BK=32), double-buffered.
__global__ __launch_bounds__(256, 2) void fused_kernel(
    const float* __restrict__ x, const float* __restrict__ qc,
    const float* __restrict__ atoms,
    const unsigned short* __restrict__ whF, const unsigned short* __restrict__ wlF,
    const float* __restrict__ bias,
    const float* __restrict__ fw1, const float* __restrict__ fb1,
    const float* __restrict__ fw2, const float* __restrict__ fb2,
    float* __restrict__ out) {
  __shared__ f32x4 bsh[2][2048];            // 2 x 32 KB
  char* ldsC = (char*)&bsh[0][0];
  const int lane = threadIdx.x & 63;
  const int wave = threadIdx.x >> 6;
  const int ptile = wave >> 1;              // 0,1: which 32-point group
  const int ch = wave & 1;                  // col-half: cols [ch*128, ch*128+128)
  const int lrow = lane & 15;
  const int lk = lane >> 4;
  const int pbase = blockIdx.x * 64 + ptile * 32;

  float bias_r[8];
#pragma unroll
  for (int ct = 0; ct < 8; ++ct) bias_r[ct] = bias[(ch * 8 + ct) * 16 + lrow];

  const char* whB = (const char*)whF;
  const char* wlB = (const char*)wlF;
  const int toff = wave * 1024 + lane * 16; // per-lane byte offset within 16KB chunk

  // stage chunk 0 into buffer 0 (4 waves cooperatively, 8 KB each)
  {
    char* db = ldsC;
    const char* gh = whB + toff;
    const char* gl = wlB + toff;
#pragma unroll
    for (int j = 0; j < 4; ++j) {
      async16(db + j * 4096 + wave * 1024, gh + j * 4096);
      async16(db + 16384 + j * 4096 + wave * 1024, gl + j * 4096);
    }
  }

  // A fragments for iter 0: 2 row-tiles
  const float* xr0 = x + (size_t)(pbase + lrow) * K_DIM + lk * 8;
  const float* xr1 = x + (size_t)(pbase + 16 + lrow) * K_DIM + lk * 8;
  f32x4 a00 = *(const f32x4*)(xr0), a01 = *(const f32x4*)(xr0 + 4);
  f32x4 a10 = *(const f32x4*)(xr1), a11 = *(const f32x4*)(xr1 + 4);
  short8 ahi0, alo0, ahi1, alo1;
  cvt8(a00, a01, &ahi0, &alo0);
  cvt8(a10, a11, &ahi1, &alo1);

  f32x4 acc[16];                            // [0..7]=tile0, [8..15]=tile1
#pragma unroll
  for (int i = 0; i < 16; ++i) acc[i] = (f32x4){0.f, 0.f, 0.f, 0.f};

  __syncthreads();                          // chunk 0 staged

  int cur = 0;
  f32x4 n00, n01, n10, n11;
#pragma unroll 1
  for (int it = 0; it < 8; ++it) {
    if (it < 7) {
      char* db = ldsC + (cur ^ 1) * 32768;
      const char* gh = whB + (it + 1) * 16384 + toff;
      const char* gl = wlB + (it + 1) * 16384 + toff;
#pragma unroll
      for (int j = 0; j < 4; ++j) {
        async16(db + j * 4096 + wave * 1024, gh + j * 4096);
        async16(db + 16384 + j * 4096 + wave * 1024, gl + j * 4096);
      }
      const float* p0 = xr0 + (it + 1) * 32;
      const float* p1 = xr1 + (it + 1) * 32;
      n00 = *(const f32x4*)(p0); n01 = *(const f32x4*)(p0 + 4);
      n10 = *(const f32x4*)(p1); n11 = *(const f32x4*)(p1 + 4);
    }
    const char* bp = ldsC + cur * 32768 + ch * 8192;   // this col-half's cts
#pragma unroll
    for (int ct = 0; ct < 8; ++ct) {
      short8 bh = *(const short8*)(bp + ct * 1024 + lane * 16);
      short8 bl = *(const short8*)(bp + 16384 + ct * 1024 + lane * 16);
      acc[ct]     = __builtin_amdgcn_mfma_f32_16x16x32_bf16(ahi0, bh, acc[ct],     0, 0, 0);
      acc[8 + ct] = __builtin_amdgcn_mfma_f32_16x16x32_bf16(ahi1, bh, acc[8 + ct], 0, 0, 0);
      acc[ct]     = __builtin_amdgcn_mfma_f32_16x16x32_bf16(alo0, bh, acc[ct],     0, 0, 0);
      acc[8 + ct] = __builtin_amdgcn_mfma_f32_16x16x32_bf16(alo1, bh, acc[8 + ct], 0, 0, 0);
      acc[ct]     = __builtin_amdgcn_mfma_f32_16x16x32_bf16(ahi0, bl, acc[ct],     0, 0, 0);
      acc[8 + ct] = __builtin_amdgcn_mfma_f32_16x16x32_bf16(ahi1, bl, acc[8 + ct], 0, 0, 0);
    }
    __syncthreads();                        // next staged & all reads of cur done
    if (it < 7) {
      cvt8(n00, n01, &ahi0, &alo0);
      cvt8(n10, n11, &ahi1, &alo1);
      cur ^= 1;
    }
  }

  // ---- omega epilogue ----
  const int batch = pbase >> 14;            // 64 | 16384 so no straddling
  const float* A = atoms + (size_t)batch * M_ATOMS * 3;
  f32x4* at4 = (f32x4*)ldsC;                // [0, 16K)
  float* red = (float*)(ldsC + 16384);      // [16K, 17K): 4 waves x 64 lanes
  for (int i = threadIdx.x; i < M_ATOMS; i += 256) {
    const float* ap = A + i * 3;
    float ax = ap[0], ay = ap[1], az = ap[2];
    f32x4 v = {ax, ay, az, ax * ax + ay * ay + az * az};
    at4[i] = v;
  }
  __syncthreads();

  // wave pair (ptile fixed, ch=0/1) splits 1024 atoms 4 ways:
  // point p = lane&31, segment = ch*2 + (lane>>5), 256 atoms each
  const int p = lane & 31;
  const int pt = pbase + p;
  const float qx = qc[(size_t)pt * 3 + 0];
  const float qy = qc[(size_t)pt * 3 + 1];
  const float qz = qc[(size_t)pt * 3 + 2];
  float m0 = 3.0e38f, m1 = 3.0e38f, m2 = 3.0e38f, m3 = 3.0e38f;
  const int i0 = (ch * 2 + (lane >> 5)) * 256;
  for (int i = i0; i < i0 + 256; i += 4) {
    f32x4 v0 = at4[i + 0], v1 = at4[i + 1], v2 = at4[i + 2], v3 = at4[i + 3];
    float d;
    d = v0[0] * qx; d = __fmaf_rn(v0[1], qy, d); d = __fmaf_rn(v0[2], qz, d);
    m0 = fminf(m0, __fmaf_rn(d, -2.0f, v0[3]));
    d = v1[0] * qx; d = __fmaf_rn(v1[1], qy, d); d = __fmaf_rn(v1[2], qz, d);
    m1 = fminf(m1, __fmaf_rn(d, -2.0f, v1[3]));
    d = v2[0] * qx; d = __fmaf_rn(v2[1], qy, d); d = __fmaf_rn(v2[2], qz, d);
    m2 = fminf(m2, __fmaf_rn(d, -2.0f, v2[3]));
    d = v3[0] * qx; d = __fmaf_rn(v3[1], qy, d); d = __fmaf_rn(v3[2], qz, d);
    m3 = fminf(m3, __fmaf_rn(d, -2.0f, v3[3]));
  }
  float md = fminf(fminf(m0, m1), fminf(m2, m3));
  red[wave * 64 + lane] = md;
  __syncthreads();
  {
    const int rb = ptile * 128;             // this ptile's two waves
    md = fminf(fminf(red[rb + p], red[rb + 32 + p]),
               fminf(red[rb + 64 + p], red[rb + 96 + p]));
  }
  md += qx * qx + qy * qy + qz * qz;        // |q-a|^2 = |q|^2 - 2 q.a + |a|^2
  float mind = sqrtf(fmaxf(md, 1.0e-4f));   // sqrt/max monotone -> commute with min

  float facc = fb2[0];
#pragma unroll
  for (int j = 0; j < 16; ++j) {
    float z = fw1[j * 3 + 0] * qx + fw1[j * 3 + 1] * qy + fw1[j * 3 + 2] * qz + fb1[j];
    facc += fw2[j] * log1pf(__expf(z));     // softplus
  }
  float ls = fminf(fmaxf(facc, 0.0f), 5.0f); // fmaxf(NaN,0)=0 == nan_to_num(clip)
  float omega_l = 30.0f * (1.0f + ls * __expf(-mind));

  // row r of tile t needs omega of point t*16+r (held by lane t*16+lk*4+j < 32)
  float om[2][4];
#pragma unroll
  for (int t = 0; t < 2; ++t)
#pragma unroll
    for (int j = 0; j < 4; ++j)
      om[t][j] = __shfl(omega_l, t * 16 + lk * 4 + j);

  // ---- store: out[pt, col] = sin(omega * (acc + bias)) ----
#pragma unroll
  for (int ct = 0; ct < 8; ++ct) {
#pragma unroll
    for (int t = 0; t < 2; ++t) {
#pragma unroll
      for (int j = 0; j < 4; ++j) {
        float pre = acc[t * 8 + ct][j] + bias_r[ct];
        out[(size_t)(pbase + t * 16 + lk * 4 + j) * O_DIM + (ch * 8 + ct) * 16 + lrow] =
            __sinf(om[t][j] * pre);
      }
    }
  }
}

extern "C" void kernel_launch(void* const* d_in, const int* in_sizes, int n_in,
                              void* d_out, int out_size, void* d_ws, size_t ws_size,
                              hipStream_t stream) {
  (void)in_sizes; (void)n_in; (void)out_size; (void)ws_size;
  const float* x     = (const float*)d_in[0];
  const float* qc    = (const float*)d_in[1];
  const float* atoms = (const float*)d_in[2];
  const float* W     = (const float*)d_in[3];
  const float* b     = (const float*)d_in[4];
  const float* fw1   = (const float*)d_in[5];
  const float* fb1   = (const float*)d_in[6];
  const float* fw2   = (const float*)d_in[7];
  const float* fb2   = (const float*)d_in[8];
  float* out = (float*)d_out;

  // workspace: whF[65536] u16 (128 KB) | wlF[65536] u16 (128 KB)
  unsigned short* whF = (unsigned short*)d_ws;
  unsigned short* wlF = whF + 65536;

  wprep_kernel<<<32, 256, 0, stream>>>(W, whF, wlF);
  fused_kernel<<<512, 256, 0, stream>>>(x, qc, atoms, whF, wlF, b,
                                        fw1, fb1, fw2, fb2, out);
}